// Round 12
// baseline (361.484 us; speedup 1.0000x reference)
//
#include <hip/hip_runtime.h>
#include <math.h>

// DigitCaps dynamic routing, fused/recompute formulation.
// u: [512,1152,8] f32, W: [1152,10,8,16] f32, out v: [512,10,16] f32.
// u_hat is NEVER materialized (377 MB). Routing logits are linear in v:
//   b_t[b,i,j] = sum_d u_hat[b,i,j,d] * Vsum[b,j,d],  Vsum = v1+...+v_{t-1}
// so each pass recomputes u_hat once from u,W and needs only Vsum (327 KB).
//
// R12: un-starve the factorized first pass. R11 evidence: first_pass
// (TB=64 GEMM body, no logit/softmax state) compiled clean (VGPR 64) and
// ran 105.6 us at only 2.25 blocks/CU (grid 576) -- the same time champion
// routing needs 4.5 blocks/CU for. It was grid-starved, not slow. This
// round: FNCHUNK 4->2, FIGROUPS 72->144 -> grid 144x8 = 1152 blocks =
// 4.5/CU (LDS 39.9 KB, 4 resident). Per-chunk staging shape byte-identical;
// only the outer trip count changes. Atomics double (WRITE ~160-190 MB,
// +~2us HBM at 17% util) -- accepted. Passes 2-3 + squash = champion
// byte-identical; downside bounded to pass 1.

#define B_  512
#define NI  1152
#define NO  10
#define DI  8
#define DO  16

constexpr int TB      = 32;              // batches per block, routing (2/thread)
constexpr int TI      = 4;               // i's per staged chunk
constexpr int NCHUNK  = 4;               // routing: chunks per block -> 16 i
constexpr int IGROUPS = NI / (TI * NCHUNK);   // 72
constexpr int EP      = 12;              // padded e-stride: rows 48B -> 16B aligned
constexpr int USTRIDE = 36;              // padded per-batch u row (32 used)

constexpr int FTB      = 64;             // first pass: batches per block (4/thread)
constexpr int FNCHUNK  = 2;              // first pass: chunks per block -> 8 i
constexpr int FIGROUPS = NI / (TI * FNCHUNK); // 144

// routing LDS: Wt 7680f (30720B) + u 32*36 (4608B) = 35328 B -> 4 blocks/CU
// first  LDS: Wt 7680f (30720B) + u 64*36 (9216B) = 39936 B -> 4 blocks/CU

// all-lanes sum over each aligned 16-lane group (d-lanes), DPP only (no LDS traffic)
__device__ __forceinline__ float row_allsum16(float x)
{
    union F { float f; int i; } a, t;
    a.f = x;  // quad_perm [1,0,3,2] : xor 1
    t.i = __builtin_amdgcn_update_dpp(0, a.i, 0xB1, 0xF, 0xF, true);  x += t.f;
    a.f = x;  // quad_perm [2,3,0,1] : xor 2
    t.i = __builtin_amdgcn_update_dpp(0, a.i, 0x4E, 0xF, 0xF, true);  x += t.f;
    a.f = x;  // row_ror:4
    t.i = __builtin_amdgcn_update_dpp(0, a.i, 0x124, 0xF, 0xF, true); x += t.f;
    a.f = x;  // row_ror:8
    t.i = __builtin_amdgcn_update_dpp(0, a.i, 0x128, 0xF, 0xF, true); x += t.f;
    return x; // every lane in the 16-group now holds the full 16-sum
}

// ---------------- pass 1: factorized GEMM (c == 0.1 exactly) ----------------
__global__ __launch_bounds__(256, 4)
void first_pass(const float* __restrict__ u, const float* __restrict__ W,
                float* __restrict__ s)
{
    __shared__ float wt[TI * NO * DO * EP];   // 7680 floats
    __shared__ float ul[FTB * USTRIDE];       // 2304 floats

    const int tid = threadIdx.x;
    const int bl  = tid >> 4;      // local batch slot 0..15
    const int d   = tid & 15;      // output dim 0..15
    const int bg0 = blockIdx.y * FTB + bl;    // +0, +16, +32, +48

    float s0[NO], s1[NO], s2[NO], s3[NO];
    #pragma unroll
    for (int j = 0; j < NO; ++j) { s0[j]=0.f; s1[j]=0.f; s2[j]=0.f; s3[j]=0.f; }

    for (int c = 0; c < FNCHUNK; ++c) {
        const int i0 = (blockIdx.x + c * FIGROUPS) * TI;

        // ---- stage W chunk (identical shape to routing_pass) ----
        {
            const float* wg = W + (size_t)i0 * (NO * DI * DO);
            #pragma unroll
            for (int it = 0; it < 5; ++it) {
                int f = it * 1024 + tid * 4;
                float4 w4 = *(const float4*)(wg + f);
                int ii   = f / 1280;
                int rem  = f - ii * 1280;
                int j    = rem >> 7;
                int rem2 = rem & 127;
                int e    = rem2 >> 4;
                int d0   = rem2 & 15;
                int base = ((ii * NO + j) * DO + d0) * EP + e;
                wt[base         ] = w4.x;
                wt[base +     EP] = w4.y;
                wt[base + 2 * EP] = w4.z;
                wt[base + 3 * EP] = w4.w;
            }
            // ---- stage u tile: 64 b x 4 i x 8 e = 2048 floats = 256 x 2 float4
            int ubl = tid >> 2;              // 0..63
            int off = (tid & 3) * 8;         // 0,8,16,24
            const float* up = u + (size_t)(blockIdx.y * FTB + ubl) * (NI * DI)
                                + (size_t)i0 * DI + off;
            float4 ua = *(const float4*)(up);
            float4 ub = *(const float4*)(up + 4);
            *(float4*)(ul + ubl * USTRIDE + off)     = ua;
            *(float4*)(ul + ubl * USTRIDE + off + 4) = ub;
        }
        __syncthreads();

        for (int ii = 0; ii < TI; ++ii) {
            float ua[DI], ub[DI], uc[DI], ud[DI];
            {
                float4 a0 = *(const float4*)(ul + bl * USTRIDE + ii * DI);
                float4 a1 = *(const float4*)(ul + bl * USTRIDE + ii * DI + 4);
                ua[0]=a0.x; ua[1]=a0.y; ua[2]=a0.z; ua[3]=a0.w;
                ua[4]=a1.x; ua[5]=a1.y; ua[6]=a1.z; ua[7]=a1.w;
                float4 b0 = *(const float4*)(ul + (bl + 16) * USTRIDE + ii * DI);
                float4 b1 = *(const float4*)(ul + (bl + 16) * USTRIDE + ii * DI + 4);
                ub[0]=b0.x; ub[1]=b0.y; ub[2]=b0.z; ub[3]=b0.w;
                ub[4]=b1.x; ub[5]=b1.y; ub[6]=b1.z; ub[7]=b1.w;
                float4 c0 = *(const float4*)(ul + (bl + 32) * USTRIDE + ii * DI);
                float4 c1 = *(const float4*)(ul + (bl + 32) * USTRIDE + ii * DI + 4);
                uc[0]=c0.x; uc[1]=c0.y; uc[2]=c0.z; uc[3]=c0.w;
                uc[4]=c1.x; uc[5]=c1.y; uc[6]=c1.z; uc[7]=c1.w;
                float4 d0v = *(const float4*)(ul + (bl + 48) * USTRIDE + ii * DI);
                float4 d1v = *(const float4*)(ul + (bl + 48) * USTRIDE + ii * DI + 4);
                ud[0]=d0v.x; ud[1]=d0v.y; ud[2]=d0v.z; ud[3]=d0v.w;
                ud[4]=d1v.x; ud[5]=d1v.y; ud[6]=d1v.z; ud[7]=d1v.w;
            }
            #pragma unroll
            for (int j = 0; j < NO; ++j) {
                const float* wr = wt + ((ii * NO + j) * DO + d) * EP;
                float4 wA = *(const float4*)(wr);
                float4 wB = *(const float4*)(wr + 4);
                s0[j] += ua[0]*wA.x + ua[1]*wA.y + ua[2]*wA.z + ua[3]*wA.w
                       + ua[4]*wB.x + ua[5]*wB.y + ua[6]*wB.z + ua[7]*wB.w;
                s1[j] += ub[0]*wA.x + ub[1]*wA.y + ub[2]*wA.z + ub[3]*wA.w
                       + ub[4]*wB.x + ub[5]*wB.y + ub[6]*wB.z + ub[7]*wB.w;
                s2[j] += uc[0]*wA.x + uc[1]*wA.y + uc[2]*wA.z + uc[3]*wA.w
                       + uc[4]*wB.x + uc[5]*wB.y + uc[6]*wB.z + uc[7]*wB.w;
                s3[j] += ud[0]*wA.x + ud[1]*wA.y + ud[2]*wA.z + ud[3]*wA.w
                       + ud[4]*wB.x + ud[5]*wB.y + ud[6]*wB.z + ud[7]*wB.w;
            }
        }
        __syncthreads();
    }

    #pragma unroll
    for (int j = 0; j < NO; ++j) {
        unsafeAtomicAdd(s + ((size_t)(bg0     ) * NO + j) * DO + d, 0.1f * s0[j]);
        unsafeAtomicAdd(s + ((size_t)(bg0 + 16) * NO + j) * DO + d, 0.1f * s1[j]);
        unsafeAtomicAdd(s + ((size_t)(bg0 + 32) * NO + j) * DO + d, 0.1f * s2[j]);
        unsafeAtomicAdd(s + ((size_t)(bg0 + 48) * NO + j) * DO + d, 0.1f * s3[j]);
    }
}

// ---------------- passes 2-3: champion routing body (unchanged) ----------------
template<bool FIRST>
__global__ __launch_bounds__(256, 4)
void routing_pass(const float* __restrict__ u, const float* __restrict__ W,
                  const float* __restrict__ vsum, float* __restrict__ s)
{
    __shared__ float wt[TI * NO * DO * EP];   // 7680 floats
    __shared__ float ul[TB * USTRIDE];        // 1152 floats

    const int tid = threadIdx.x;
    const int bl  = tid >> 4;      // local batch slot 0..15
    const int d   = tid & 15;      // output dim 0..15
    const int bg0 = blockIdx.y * TB + bl;
    const int bg1 = bg0 + 16;

    float vs0[NO], vs1[NO];
    if (!FIRST) {
        #pragma unroll
        for (int j = 0; j < NO; ++j) {
            vs0[j] = vsum[((size_t)bg0 * NO + j) * DO + d];
            vs1[j] = vsum[((size_t)bg1 * NO + j) * DO + d];
        }
    }
    float s0[NO], s1[NO];
    #pragma unroll
    for (int j = 0; j < NO; ++j) { s0[j] = 0.f; s1[j] = 0.f; }

    for (int c = 0; c < NCHUNK; ++c) {
        const int i0 = (blockIdx.x + c * IGROUPS) * TI;

        {
            const float* wg = W + (size_t)i0 * (NO * DI * DO);
            #pragma unroll
            for (int it = 0; it < 5; ++it) {
                int f = it * 1024 + tid * 4;
                float4 w4 = *(const float4*)(wg + f);
                int ii   = f / 1280;
                int rem  = f - ii * 1280;
                int j    = rem >> 7;
                int rem2 = rem & 127;
                int e    = rem2 >> 4;
                int d0   = rem2 & 15;
                int base = ((ii * NO + j) * DO + d0) * EP + e;
                wt[base         ] = w4.x;
                wt[base +     EP] = w4.y;
                wt[base + 2 * EP] = w4.z;
                wt[base + 3 * EP] = w4.w;
            }
            int f   = tid * 4;
            int ubl = f >> 5;
            int off = f & 31;
            float4 u4 = *(const float4*)(u + (size_t)(blockIdx.y * TB + ubl) * (NI * DI)
                                           + (size_t)i0 * DI + off);
            *(float4*)(ul + ubl * USTRIDE + off) = u4;
        }
        __syncthreads();

        for (int ii = 0; ii < TI; ++ii) {
            float ua[DI], ub[DI];
            {
                float4 a0 = *(const float4*)(ul + bl * USTRIDE + ii * DI);
                float4 a1 = *(const float4*)(ul + bl * USTRIDE + ii * DI + 4);
                ua[0]=a0.x; ua[1]=a0.y; ua[2]=a0.z; ua[3]=a0.w;
                ua[4]=a1.x; ua[5]=a1.y; ua[6]=a1.z; ua[7]=a1.w;
                float4 b0 = *(const float4*)(ul + (bl + 16) * USTRIDE + ii * DI);
                float4 b1 = *(const float4*)(ul + (bl + 16) * USTRIDE + ii * DI + 4);
                ub[0]=b0.x; ub[1]=b0.y; ub[2]=b0.z; ub[3]=b0.w;
                ub[4]=b1.x; ub[5]=b1.y; ub[6]=b1.z; ub[7]=b1.w;
            }
            float uh0[NO], uh1[NO];
            float c0[NO],  c1[NO];
            #pragma unroll
            for (int j = 0; j < NO; ++j) {
                const float* wr = wt + ((ii * NO + j) * DO + d) * EP;
                float4 wA = *(const float4*)(wr);
                float4 wB = *(const float4*)(wr + 4);
                float h0 = ua[0]*wA.x + ua[1]*wA.y + ua[2]*wA.z + ua[3]*wA.w
                         + ua[4]*wB.x + ua[5]*wB.y + ua[6]*wB.z + ua[7]*wB.w;
                float h1 = ub[0]*wA.x + ub[1]*wA.y + ub[2]*wA.z + ub[3]*wA.w
                         + ub[4]*wB.x + ub[5]*wB.y + ub[6]*wB.z + ub[7]*wB.w;
                uh0[j] = h0;
                uh1[j] = h1;
                if (!FIRST) {
                    c0[j] = row_allsum16(h0 * vs0[j]);
                    c1[j] = row_allsum16(h1 * vs1[j]);
                }
            }
            if (FIRST) {
                #pragma unroll
                for (int j = 0; j < NO; ++j) {
                    s0[j] += 0.1f * uh0[j];
                    s1[j] += 0.1f * uh1[j];
                }
            } else {
                float m0 = c0[0], m1 = c1[0];
                #pragma unroll
                for (int j = 1; j < NO; ++j) { m0 = fmaxf(m0, c0[j]); m1 = fmaxf(m1, c1[j]); }
                float sum0 = 0.f, sum1 = 0.f;
                #pragma unroll
                for (int j = 0; j < NO; ++j) {
                    float e0 = __expf(c0[j] - m0); c0[j] = e0; sum0 += e0;
                    float e1 = __expf(c1[j] - m1); c1[j] = e1; sum1 += e1;
                }
                float inv0 = 1.f / sum0, inv1 = 1.f / sum1;
                #pragma unroll
                for (int j = 0; j < NO; ++j) {
                    s0[j] += (c0[j] * inv0) * uh0[j];
                    s1[j] += (c1[j] * inv1) * uh1[j];
                }
            }
        }
        __syncthreads();
    }

    #pragma unroll
    for (int j = 0; j < NO; ++j) {
        unsafeAtomicAdd(s + ((size_t)bg0 * NO + j) * DO + d, s0[j]);
        unsafeAtomicAdd(s + ((size_t)bg1 * NO + j) * DO + d, s1[j]);
    }
}

// v = squash(s); vsum += v; out = v; s = 0 (ready for next pass)
__global__ void squash_k(float* __restrict__ s, float* __restrict__ vsum,
                         float* __restrict__ out)
{
    int t = blockIdx.x * blockDim.x + threadIdx.x;   // (b*NO + j)
    if (t >= B_ * NO) return;
    float* sp = s + (size_t)t * DO;
    float4 a = *(const float4*)(sp);
    float4 b = *(const float4*)(sp + 4);
    float4 c = *(const float4*)(sp + 8);
    float4 e = *(const float4*)(sp + 12);
    float sq = a.x*a.x + a.y*a.y + a.z*a.z + a.w*a.w
             + b.x*b.x + b.y*b.y + b.z*b.z + b.w*b.w
             + c.x*c.x + c.y*c.y + c.z*c.z + c.w*c.w
             + e.x*e.x + e.y*e.y + e.z*e.z + e.w*e.w;
    float factor = sq / (sqrtf(sq) * (1.f + sq) + 1e-30f);

    float4 va = make_float4(factor*a.x, factor*a.y, factor*a.z, factor*a.w);
    float4 vb = make_float4(factor*b.x, factor*b.y, factor*b.z, factor*b.w);
    float4 vc = make_float4(factor*c.x, factor*c.y, factor*c.z, factor*c.w);
    float4 ve = make_float4(factor*e.x, factor*e.y, factor*e.z, factor*e.w);

    float* op = out + (size_t)t * DO;
    *(float4*)(op)      = va;
    *(float4*)(op + 4)  = vb;
    *(float4*)(op + 8)  = vc;
    *(float4*)(op + 12) = ve;

    float* vp = vsum + (size_t)t * DO;
    float4 p0 = *(const float4*)(vp);
    float4 p1 = *(const float4*)(vp + 4);
    float4 p2 = *(const float4*)(vp + 8);
    float4 p3 = *(const float4*)(vp + 12);
    p0.x += va.x; p0.y += va.y; p0.z += va.z; p0.w += va.w;
    p1.x += vb.x; p1.y += vb.y; p1.z += vb.z; p1.w += vb.w;
    p2.x += vc.x; p2.y += vc.y; p2.z += vc.z; p2.w += vc.w;
    p3.x += ve.x; p3.y += ve.y; p3.z += ve.z; p3.w += ve.w;
    *(float4*)(vp)      = p0;
    *(float4*)(vp + 4)  = p1;
    *(float4*)(vp + 8)  = p2;
    *(float4*)(vp + 12) = p3;

    float4 z = make_float4(0.f, 0.f, 0.f, 0.f);
    *(float4*)(sp)      = z;
    *(float4*)(sp + 4)  = z;
    *(float4*)(sp + 8)  = z;
    *(float4*)(sp + 12) = z;
}

extern "C" void kernel_launch(void* const* d_in, const int* in_sizes, int n_in,
                              void* d_out, int out_size, void* d_ws, size_t ws_size,
                              hipStream_t stream)
{
    (void)in_sizes; (void)n_in; (void)out_size; (void)ws_size;
    const float* u = (const float*)d_in[0];
    const float* W = (const float*)d_in[1];
    // d_in[2] is r; fixed at 3 by the reference setup -> 3 unrolled rounds below.
    float* out  = (float*)d_out;
    float* s    = (float*)d_ws;                 // [512,10,16]
    float* vsum = s + B_ * NO * DO;             // [512,10,16]

    hipMemsetAsync(d_ws, 0, (size_t)2 * B_ * NO * DO * sizeof(float), stream);

    dim3 gridf(FIGROUPS, B_ / FTB), blk(256);  // 144 x 8 = 1152 blocks
    dim3 grid (IGROUPS,  B_ / TB);             // 72 x 16 = 1152 blocks
    dim3 sg((B_ * NO + 255) / 256), sb(256);

    first_pass<<<gridf, blk, 0, stream>>>(u, W, s);
    squash_k<<<sg, sb, 0, stream>>>(s, vsum, out);
    routing_pass<false><<<grid, blk, 0, stream>>>(u, W, vsum, s);
    squash_k<<<sg, sb, 0, stream>>>(s, vsum, out);
    routing_pass<false><<<grid, blk, 0, stream>>>(u, W, vsum, s);
    squash_k<<<sg, sb, 0, stream>>>(s, vsum, out);
}

// Round 13
// 315.231 us; speedup vs baseline: 1.1467x; 1.1467x over previous
//
#include <hip/hip_runtime.h>
#include <math.h>

// DigitCaps dynamic routing, fused/recompute formulation.
// u: [512,1152,8] f32, W: [1152,10,8,16] f32, out v: [512,10,16] f32.
// u_hat is NEVER materialized (377 MB). Routing logits are linear in v:
//   b_t[b,i,j] = sum_d u_hat[b,i,j,d] * Vsum[b,j,d],  Vsum = v1+...+v_{t-1}
// so each pass recomputes u_hat once from u,W and needs only Vsum (327 KB).
//
// R13 (final): measured champion, locked. 13 benches mapped the landscape:
//  - This shape (TI=4 unguarded staging, u in LDS, EP=12 b128 W reads,
//    lb(256,4), 2 batches/thread, DPP logit reduce): 105.5 us/pass,
//    64 VGPR, FETCH 65 / WRITE 79 MB. Reproduced at 316.5 and 314.5 us.
//  - Structural variants (guarded staging, reg prefetch, direct-global u,
//    smaller tiles: R4/R5/R7/R8/R10) all tripped hipcc's register-pressure
//    cliff -> scratch-traffic storms (200 MB-1.6 GB/pass), 1.1-3x slower.
//  - Work-split variants (factorized first pass, R11/R12): clean codegen
//    but grid-starved (2.25 blk/CU) or atomic-contended (144 writers/line);
//    both slower than just running the routing body three times.
//  - Within clean codegen, pass time is invariant to occupancy (21->36%),
//    VALU work (FIRST vs non-FIRST), LDS instr count (b64 vs b128): a
//    latency-bound plateau. No pipe >57%; the escape routes all require
//    code shapes the compiler won't allocate cleanly for this body.

#define B_  512
#define NI  1152
#define NO  10
#define DI  8
#define DO  16

constexpr int TB      = 32;              // batches per block (2 per thread)
constexpr int TI      = 4;               // i's per staged chunk
constexpr int NCHUNK  = 4;               // chunks per block -> 16 i per block
constexpr int IGROUPS = NI / (TI * NCHUNK);   // 72
constexpr int EP      = 12;              // padded e-stride: rows 48B -> 16B aligned
constexpr int USTRIDE = 36;              // padded per-batch u row (32 used)

// LDS: Wt 4*10*16*12 = 7680 f (30720 B) + u 32*36 = 1152 f (4608 B) = 35328 B
// -> 4 blocks/CU, VGPR 64 (measured), clean codegen.

// all-lanes sum over each aligned 16-lane group (d-lanes), DPP only (no LDS traffic)
__device__ __forceinline__ float row_allsum16(float x)
{
    union F { float f; int i; } a, t;
    a.f = x;  // quad_perm [1,0,3,2] : xor 1
    t.i = __builtin_amdgcn_update_dpp(0, a.i, 0xB1, 0xF, 0xF, true);  x += t.f;
    a.f = x;  // quad_perm [2,3,0,1] : xor 2
    t.i = __builtin_amdgcn_update_dpp(0, a.i, 0x4E, 0xF, 0xF, true);  x += t.f;
    a.f = x;  // row_ror:4
    t.i = __builtin_amdgcn_update_dpp(0, a.i, 0x124, 0xF, 0xF, true); x += t.f;
    a.f = x;  // row_ror:8
    t.i = __builtin_amdgcn_update_dpp(0, a.i, 0x128, 0xF, 0xF, true); x += t.f;
    return x; // every lane in the 16-group now holds the full 16-sum
}

template<bool FIRST>
__global__ __launch_bounds__(256, 4)
void routing_pass(const float* __restrict__ u, const float* __restrict__ W,
                  const float* __restrict__ vsum, float* __restrict__ s)
{
    __shared__ float wt[TI * NO * DO * EP];   // 7680 floats
    __shared__ float ul[TB * USTRIDE];        // 1152 floats

    const int tid = threadIdx.x;
    const int bl  = tid >> 4;      // local batch slot 0..15
    const int d   = tid & 15;      // output dim 0..15
    const int bg0 = blockIdx.y * TB + bl;
    const int bg1 = bg0 + 16;

    float vs0[NO], vs1[NO];
    if (!FIRST) {
        #pragma unroll
        for (int j = 0; j < NO; ++j) {
            vs0[j] = vsum[((size_t)bg0 * NO + j) * DO + d];
            vs1[j] = vsum[((size_t)bg1 * NO + j) * DO + d];
        }
    }
    float s0[NO], s1[NO];
    #pragma unroll
    for (int j = 0; j < NO; ++j) { s0[j] = 0.f; s1[j] = 0.f; }

    for (int c = 0; c < NCHUNK; ++c) {
        const int i0 = (blockIdx.x + c * IGROUPS) * TI;

        // ---- stage W chunk (contiguous 5120 floats) into LDS, transposed to
        //      wt[((ii*10+j)*16+d)*EP + e] so each thread reads its 8 e's contiguously
        {
            const float* wg = W + (size_t)i0 * (NO * DI * DO);
            #pragma unroll
            for (int it = 0; it < 5; ++it) {
                int f = it * 1024 + tid * 4;
                float4 w4 = *(const float4*)(wg + f);
                int ii   = f / 1280;
                int rem  = f - ii * 1280;
                int j    = rem >> 7;
                int rem2 = rem & 127;
                int e    = rem2 >> 4;
                int d0   = rem2 & 15;
                int base = ((ii * NO + j) * DO + d0) * EP + e;
                wt[base         ] = w4.x;
                wt[base +     EP] = w4.y;
                wt[base + 2 * EP] = w4.z;
                wt[base + 3 * EP] = w4.w;
            }
            // ---- stage u tile: 32 b x 4 i x 8 e = 1024 floats
            int f   = tid * 4;
            int ubl = f >> 5;          // 32 floats per batch row
            int off = f & 31;
            float4 u4 = *(const float4*)(u + (size_t)(blockIdx.y * TB + ubl) * (NI * DI)
                                           + (size_t)i0 * DI + off);
            *(float4*)(ul + ubl * USTRIDE + off) = u4;
        }
        __syncthreads();

        for (int ii = 0; ii < TI; ++ii) {
            float ua[DI], ub[DI];
            {
                float4 a0 = *(const float4*)(ul + bl * USTRIDE + ii * DI);
                float4 a1 = *(const float4*)(ul + bl * USTRIDE + ii * DI + 4);
                ua[0]=a0.x; ua[1]=a0.y; ua[2]=a0.z; ua[3]=a0.w;
                ua[4]=a1.x; ua[5]=a1.y; ua[6]=a1.z; ua[7]=a1.w;
                float4 b0 = *(const float4*)(ul + (bl + 16) * USTRIDE + ii * DI);
                float4 b1 = *(const float4*)(ul + (bl + 16) * USTRIDE + ii * DI + 4);
                ub[0]=b0.x; ub[1]=b0.y; ub[2]=b0.z; ub[3]=b0.w;
                ub[4]=b1.x; ub[5]=b1.y; ub[6]=b1.z; ub[7]=b1.w;
            }
            float uh0[NO], uh1[NO];
            float c0[NO],  c1[NO];
            #pragma unroll
            for (int j = 0; j < NO; ++j) {
                const float* wr = wt + ((ii * NO + j) * DO + d) * EP;
                float4 wA = *(const float4*)(wr);      // 16B aligned (EP=12 -> 48B rows)
                float4 wB = *(const float4*)(wr + 4);
                float h0 = ua[0]*wA.x + ua[1]*wA.y + ua[2]*wA.z + ua[3]*wA.w
                         + ua[4]*wB.x + ua[5]*wB.y + ua[6]*wB.z + ua[7]*wB.w;
                float h1 = ub[0]*wA.x + ub[1]*wA.y + ub[2]*wA.z + ub[3]*wA.w
                         + ub[4]*wB.x + ub[5]*wB.y + ub[6]*wB.z + ub[7]*wB.w;
                uh0[j] = h0;
                uh1[j] = h1;
                if (!FIRST) {
                    c0[j] = row_allsum16(h0 * vs0[j]);   // logit[b0,i,j]
                    c1[j] = row_allsum16(h1 * vs1[j]);   // logit[b1,i,j]
                }
            }
            if (FIRST) {
                // b == 0 -> softmax over 10 zeros -> c = 0.1 exactly
                #pragma unroll
                for (int j = 0; j < NO; ++j) {
                    s0[j] += 0.1f * uh0[j];
                    s1[j] += 0.1f * uh1[j];
                }
            } else {
                float m0 = c0[0], m1 = c1[0];
                #pragma unroll
                for (int j = 1; j < NO; ++j) { m0 = fmaxf(m0, c0[j]); m1 = fmaxf(m1, c1[j]); }
                float sum0 = 0.f, sum1 = 0.f;
                #pragma unroll
                for (int j = 0; j < NO; ++j) {
                    float e0 = __expf(c0[j] - m0); c0[j] = e0; sum0 += e0;
                    float e1 = __expf(c1[j] - m1); c1[j] = e1; sum1 += e1;
                }
                float inv0 = 1.f / sum0, inv1 = 1.f / sum1;
                #pragma unroll
                for (int j = 0; j < NO; ++j) {
                    s0[j] += (c0[j] * inv0) * uh0[j];
                    s1[j] += (c1[j] * inv1) * uh1[j];
                }
            }
        }
        __syncthreads();   // protect LDS before next chunk's staging
    }

    #pragma unroll
    for (int j = 0; j < NO; ++j) {
        unsafeAtomicAdd(s + ((size_t)bg0 * NO + j) * DO + d, s0[j]);
        unsafeAtomicAdd(s + ((size_t)bg1 * NO + j) * DO + d, s1[j]);
    }
}

// v = squash(s); vsum += v; out = v; s = 0 (ready for next pass)
__global__ void squash_k(float* __restrict__ s, float* __restrict__ vsum,
                         float* __restrict__ out)
{
    int t = blockIdx.x * blockDim.x + threadIdx.x;   // (b*NO + j)
    if (t >= B_ * NO) return;
    float* sp = s + (size_t)t * DO;
    float4 a = *(const float4*)(sp);
    float4 b = *(const float4*)(sp + 4);
    float4 c = *(const float4*)(sp + 8);
    float4 e = *(const float4*)(sp + 12);
    float sq = a.x*a.x + a.y*a.y + a.z*a.z + a.w*a.w
             + b.x*b.x + b.y*b.y + b.z*b.z + b.w*b.w
             + c.x*c.x + c.y*c.y + c.z*c.z + c.w*c.w
             + e.x*e.x + e.y*e.y + e.z*e.z + e.w*e.w;
    float factor = sq / (sqrtf(sq) * (1.f + sq) + 1e-30f);

    float4 va = make_float4(factor*a.x, factor*a.y, factor*a.z, factor*a.w);
    float4 vb = make_float4(factor*b.x, factor*b.y, factor*b.z, factor*b.w);
    float4 vc = make_float4(factor*c.x, factor*c.y, factor*c.z, factor*c.w);
    float4 ve = make_float4(factor*e.x, factor*e.y, factor*e.z, factor*e.w);

    float* op = out + (size_t)t * DO;
    *(float4*)(op)      = va;
    *(float4*)(op + 4)  = vb;
    *(float4*)(op + 8)  = vc;
    *(float4*)(op + 12) = ve;

    float* vp = vsum + (size_t)t * DO;
    float4 p0 = *(const float4*)(vp);
    float4 p1 = *(const float4*)(vp + 4);
    float4 p2 = *(const float4*)(vp + 8);
    float4 p3 = *(const float4*)(vp + 12);
    p0.x += va.x; p0.y += va.y; p0.z += va.z; p0.w += va.w;
    p1.x += vb.x; p1.y += vb.y; p1.z += vb.z; p1.w += vb.w;
    p2.x += vc.x; p2.y += vc.y; p2.z += vc.z; p2.w += vc.w;
    p3.x += ve.x; p3.y += ve.y; p3.z += ve.z; p3.w += ve.w;
    *(float4*)(vp)      = p0;
    *(float4*)(vp + 4)  = p1;
    *(float4*)(vp + 8)  = p2;
    *(float4*)(vp + 12) = p3;

    float4 z = make_float4(0.f, 0.f, 0.f, 0.f);
    *(float4*)(sp)      = z;
    *(float4*)(sp + 4)  = z;
    *(float4*)(sp + 8)  = z;
    *(float4*)(sp + 12) = z;
}

extern "C" void kernel_launch(void* const* d_in, const int* in_sizes, int n_in,
                              void* d_out, int out_size, void* d_ws, size_t ws_size,
                              hipStream_t stream)
{
    (void)in_sizes; (void)n_in; (void)out_size; (void)ws_size;
    const float* u = (const float*)d_in[0];
    const float* W = (const float*)d_in[1];
    // d_in[2] is r; fixed at 3 by the reference setup -> 3 unrolled rounds below.
    float* out  = (float*)d_out;
    float* s    = (float*)d_ws;                 // [512,10,16]
    float* vsum = s + B_ * NO * DO;             // [512,10,16]

    hipMemsetAsync(d_ws, 0, (size_t)2 * B_ * NO * DO * sizeof(float), stream);

    dim3 grid(IGROUPS, B_ / TB), blk(256);
    dim3 sg((B_ * NO + 255) / 256), sb(256);

    routing_pass<true ><<<grid, blk, 0, stream>>>(u, W, vsum, s);
    squash_k<<<sg, sb, 0, stream>>>(s, vsum, out);
    routing_pass<false><<<grid, blk, 0, stream>>>(u, W, vsum, s);
    squash_k<<<sg, sb, 0, stream>>>(s, vsum, out);
    routing_pass<false><<<grid, blk, 0, stream>>>(u, W, vsum, s);
    squash_k<<<sg, sb, 0, stream>>>(s, vsum, out);
}